// Round 1
// baseline (577.411 us; speedup 1.0000x reference)
//
#include <hip/hip_runtime.h>
#include <hip/hip_bf16.h>
#include <math.h>

// ---------------- dtype detection: int64 vs int32 edge_index ----------------
// If edge data is really int64, every value read as int64 is in [0, n).
// If it is int32 pairs, an int64 read combines two random indices -> huge.
__global__ void k_detect(const void* edges, long long nn, int* flag) {
    const long long* e64 = (const long long*)edges;
    int ok = 1;
    for (int i = 0; i < 8; ++i) {
        long long v = e64[i];
        if (v < 0 || v >= nn) { ok = 0; break; }
    }
    *flag = ok;
}

__global__ void k_init_deg(float* deg, int n) {
    int i = blockIdx.x * blockDim.x + threadIdx.x;
    if (i < n) deg[i] = 1.0f;  // self-loop
}

__global__ void k_deg(const void* edges, const int* flag, long long E, float* deg) {
    long long e = blockIdx.x * (long long)blockDim.x + threadIdx.x;
    if (e >= E) return;
    int dst;
    if (*flag) dst = (int)((const long long*)edges)[E + e];
    else       dst = ((const int*)edges)[E + e];
    unsafeAtomicAdd(&deg[dst], 1.0f);
}

__global__ void k_dinv(const float* deg, float* dinv, int n) {
    int i = blockIdx.x * blockDim.x + threadIdx.x;
    if (i < n) dinv[i] = rsqrtf(deg[i]);
}

// ---------------- GEMM1: h1[n,64] = x[n,64] @ W1[64,64] ----------------
__global__ __launch_bounds__(256) void k_gemm1(const float* __restrict__ x,
                                               const float* __restrict__ W,
                                               float* __restrict__ h) {
    __shared__ float Ws[64][64];
    __shared__ float xs[16][64];
    int t = threadIdx.x;
    for (int i = t; i < 64 * 64; i += 256) Ws[i >> 6][i & 63] = W[i];
    long long row0 = (long long)blockIdx.x * 16;
    ((float4*)xs)[t] = ((const float4*)(x + row0 * 64))[t];
    __syncthreads();
    int r = t >> 4;
    int c0 = (t & 15) * 4;
    float4 acc = {0.f, 0.f, 0.f, 0.f};
#pragma unroll
    for (int k = 0; k < 64; ++k) {
        float xv = xs[r][k];
        float4 wv = *((const float4*)&Ws[k][c0]);
        acc.x += xv * wv.x; acc.y += xv * wv.y;
        acc.z += xv * wv.z; acc.w += xv * wv.w;
    }
    *((float4*)(h + (row0 + r) * 64 + c0)) = acc;
}

// ---------------- GEMM2: h2[n,16] = h1r[n,64] @ W2[64,16] ----------------
__global__ __launch_bounds__(256) void k_gemm2(const float* __restrict__ h,
                                               const float* __restrict__ W,
                                               float* __restrict__ h2) {
    __shared__ float Ws[64 * 16];
    __shared__ float xs[16][64];
    int t = threadIdx.x;
    for (int i = t; i < 64 * 16; i += 256) Ws[i] = W[i];
    long long row0 = (long long)blockIdx.x * 16;
    ((float4*)xs)[t] = ((const float4*)(h + row0 * 64))[t];
    __syncthreads();
    int r = t >> 4, c = t & 15;
    float acc = 0.f;
#pragma unroll
    for (int k = 0; k < 64; ++k) acc += xs[r][k] * Ws[k * 16 + c];
    h2[(row0 + r) * 16 + c] = acc;
}

// ---------------- edge aggregation, 64 features: wave per edge ----------------
__global__ __launch_bounds__(256) void k_agg64(const void* edges, const int* flag,
                                               long long E,
                                               const float* __restrict__ dinv,
                                               const float* __restrict__ h,
                                               float* out) {
    long long tid = (long long)blockIdx.x * 256 + threadIdx.x;
    long long e = tid >> 6;
    if (e >= E) return;
    int f = threadIdx.x & 63;
    int s, d;
    if (*flag) {
        const long long* ee = (const long long*)edges;
        s = (int)ee[e]; d = (int)ee[E + e];
    } else {
        const int* ee = (const int*)edges;
        s = ee[e]; d = ee[E + e];
    }
    float norm = dinv[s] * dinv[d];
    float v = norm * h[(long long)s * 64 + f];
    unsafeAtomicAdd(out + (long long)d * 64 + f, v);
}

// ---------------- edge aggregation, 16 features ----------------
__global__ __launch_bounds__(256) void k_agg16(const void* edges, const int* flag,
                                               long long E,
                                               const float* __restrict__ dinv,
                                               const float* __restrict__ h,
                                               float* out) {
    long long tid = (long long)blockIdx.x * 256 + threadIdx.x;
    long long e = tid >> 4;
    if (e >= E) return;
    int f = threadIdx.x & 15;
    int s, d;
    if (*flag) {
        const long long* ee = (const long long*)edges;
        s = (int)ee[e]; d = (int)ee[E + e];
    } else {
        const int* ee = (const int*)edges;
        s = ee[e]; d = ee[E + e];
    }
    float norm = dinv[s] * dinv[d];
    float v = norm * h[(long long)s * 16 + f];
    unsafeAtomicAdd(out + (long long)d * 16 + f, v);
}

// ------------- post1: acc1 = relu(acc1 + dinv^2*h1 + b1) (in place) -------------
__global__ void k_post1(const float* __restrict__ h1, const float* __restrict__ b,
                        const float* __restrict__ dinv, float* acc, long long total) {
    long long i = (long long)blockIdx.x * 256 + threadIdx.x;
    if (i >= total) return;
    int row = (int)(i >> 6), f = (int)(i & 63);
    float di = dinv[row];
    float v = acc[i] + di * di * h1[i] + b[f];
    acc[i] = v > 0.f ? v : 0.f;
}

// ------------- post2: out = log_softmax(out + dinv^2*h2 + b2) per row of 16 -------------
__global__ void k_post2(const float* __restrict__ h2, const float* __restrict__ b,
                        const float* __restrict__ dinv, float* out, long long total) {
    long long i = (long long)blockIdx.x * 256 + threadIdx.x;
    if (i >= total) return;
    int row = (int)(i >> 4), c = (int)(i & 15);
    float di = dinv[row];
    float v = out[i] + di * di * h2[i] + b[c];
    float m = v;
#pragma unroll
    for (int o = 8; o >= 1; o >>= 1) m = fmaxf(m, __shfl_xor(m, o, 16));
    float ex = __expf(v - m);
#pragma unroll
    for (int o = 8; o >= 1; o >>= 1) ex += __shfl_xor(ex, o, 16);
    // ex now holds sum over the 16-lane group
    float lse = __logf(ex);
    // recompute own exp argument: v - m
    out[i] = (v - m) - lse;
}

extern "C" void kernel_launch(void* const* d_in, const int* in_sizes, int n_in,
                              void* d_out, int out_size, void* d_ws, size_t ws_size,
                              hipStream_t stream) {
    const float* x  = (const float*)d_in[0];
    const void*  ei = d_in[1];
    const float* W1 = (const float*)d_in[2];
    const float* b1 = (const float*)d_in[3];
    const float* W2 = (const float*)d_in[4];
    const float* b2 = (const float*)d_in[5];

    long long dh   = in_sizes[3];          // 64
    long long din  = in_sizes[2] / dh;     // 64
    long long n    = in_sizes[0] / din;    // 50000
    long long E    = (long long)in_sizes[1] / 2;  // 1.6M

    char* ws = (char*)d_ws;
    int* flag   = (int*)ws;               ws += 256;
    float* deg  = (float*)ws;             ws += ((n * 4 + 255) / 256) * 256;
    float* dinv = (float*)ws;             ws += ((n * 4 + 255) / 256) * 256;
    float* h1   = (float*)ws;             ws += n * 64 * 4;
    float* acc1 = (float*)ws;             ws += n * 64 * 4;
    float* h2   = (float*)ws;             // n*16*4

    float* out = (float*)d_out;

    hipMemsetAsync(acc1, 0, (size_t)(n * 64 * 4), stream);
    hipMemsetAsync(out, 0, (size_t)out_size * 4, stream);

    k_detect<<<1, 1, 0, stream>>>(ei, n, flag);
    k_init_deg<<<(int)((n + 255) / 256), 256, 0, stream>>>(deg, (int)n);
    k_deg<<<(int)((E + 255) / 256), 256, 0, stream>>>(ei, flag, E, deg);
    k_dinv<<<(int)((n + 255) / 256), 256, 0, stream>>>(deg, dinv, (int)n);

    // layer 1
    k_gemm1<<<(int)(n / 16), 256, 0, stream>>>(x, W1, h1);
    k_agg64<<<(int)((E * 64 + 255) / 256), 256, 0, stream>>>(ei, flag, E, dinv, h1, acc1);
    k_post1<<<(int)((n * 64 + 255) / 256), 256, 0, stream>>>(h1, b1, dinv, acc1, n * 64);

    // layer 2
    k_gemm2<<<(int)(n / 16), 256, 0, stream>>>(acc1, W2, h2);
    k_agg16<<<(int)((E * 16 + 255) / 256), 256, 0, stream>>>(ei, flag, E, dinv, h2, out);
    k_post2<<<(int)((n * 16 + 255) / 256), 256, 0, stream>>>(h2, b2, dinv, out, n * 16);
}

// Round 2
// 360.420 us; speedup vs baseline: 1.6021x; 1.6021x over previous
//
#include <hip/hip_runtime.h>
#include <hip/hip_bf16.h>
#include <math.h>

#define THREADS 256

// ---------------- dtype detection: int64 vs int32 edge_index ----------------
__global__ void k_detect(const void* edges, long long nn, int* flag) {
    const long long* e64 = (const long long*)edges;
    int ok = 1;
    for (int i = 0; i < 8; ++i) {
        long long v = e64[i];
        if (v < 0 || v >= nn) { ok = 0; break; }
    }
    *flag = ok;
}

// ---------------- in-degree counts (int) ----------------
__global__ void k_count(const void* edges, const int* __restrict__ flag,
                        long long E, int* counts) {
    long long e = blockIdx.x * (long long)blockDim.x + threadIdx.x;
    if (e >= E) return;
    int d = (*flag) ? (int)((const long long*)edges)[E + e]
                    : ((const int*)edges)[E + e];
    atomicAdd(&counts[d], 1);
}

// ---------------- 2-level exclusive scan ----------------
__global__ void k_scanA(const int* __restrict__ counts, int n,
                        int* rowstart, int* bsum, float* dinv) {
    __shared__ int tmp[THREADS];
    int t = threadIdx.x;
    int i = blockIdx.x * THREADS + t;
    int v = (i < n) ? counts[i] : 0;
    if (i < n) dinv[i] = rsqrtf((float)(v + 1));  // deg includes self-loop
    tmp[t] = v;
    __syncthreads();
    for (int off = 1; off < THREADS; off <<= 1) {
        int a = (t >= off) ? tmp[t - off] : 0;
        __syncthreads();
        tmp[t] += a;
        __syncthreads();
    }
    if (i < n) rowstart[i] = tmp[t] - v;          // exclusive within block
    if (t == THREADS - 1) bsum[blockIdx.x] = tmp[t];
}

__global__ void k_scanB(const int* __restrict__ bsum, int nb, int* boff) {
    __shared__ int tmp[THREADS];
    int t = threadIdx.x;
    int v = (t < nb) ? bsum[t] : 0;
    tmp[t] = v;
    __syncthreads();
    for (int off = 1; off < THREADS; off <<= 1) {
        int a = (t >= off) ? tmp[t - off] : 0;
        __syncthreads();
        tmp[t] += a;
        __syncthreads();
    }
    if (t < nb) boff[t] = tmp[t] - v;
}

__global__ void k_scanC(int* rowstart, const int* __restrict__ boff,
                        int* cursor, int n) {
    int i = blockIdx.x * THREADS + threadIdx.x;
    if (i < n) {
        int r = rowstart[i] + boff[i >> 8];
        rowstart[i] = r;
        cursor[i] = r;
    }
}

// ---------------- scatter edges into dst-bucketed CSR ----------------
__global__ void k_scatter(const void* edges, const int* __restrict__ flag,
                          long long E, int* cursor, int* sorted_src) {
    long long e = blockIdx.x * (long long)blockDim.x + threadIdx.x;
    if (e >= E) return;
    int s, d;
    if (*flag) {
        const long long* ee = (const long long*)edges;
        s = (int)ee[e]; d = (int)ee[E + e];
    } else {
        const int* ee = (const int*)edges;
        s = ee[e]; d = ee[E + e];
    }
    int pos = atomicAdd(&cursor[d], 1);
    sorted_src[pos] = s;
}

// ---------------- GEMM1: h1s[n,64] = dinv * (x[n,64] @ W1[64,64]) ----------------
__global__ __launch_bounds__(256) void k_gemm1(const float* __restrict__ x,
                                               const float* __restrict__ W,
                                               const float* __restrict__ dinv,
                                               float* __restrict__ h) {
    __shared__ float Ws[64][64];
    __shared__ float xs[16][64];
    int t = threadIdx.x;
    for (int i = t; i < 64 * 64; i += 256) Ws[i >> 6][i & 63] = W[i];
    long long row0 = (long long)blockIdx.x * 16;
    ((float4*)xs)[t] = ((const float4*)(x + row0 * 64))[t];
    __syncthreads();
    int r = t >> 4, c0 = (t & 15) * 4;
    float4 acc = {0.f, 0.f, 0.f, 0.f};
#pragma unroll
    for (int k = 0; k < 64; ++k) {
        float xv = xs[r][k];
        float4 wv = *((const float4*)&Ws[k][c0]);
        acc.x += xv * wv.x; acc.y += xv * wv.y;
        acc.z += xv * wv.z; acc.w += xv * wv.w;
    }
    float di = dinv[row0 + r];
    acc.x *= di; acc.y *= di; acc.z *= di; acc.w *= di;
    *((float4*)(h + (row0 + r) * 64 + c0)) = acc;
}

// ---------------- GEMM2: h2s[n,16] = dinv * (out1[n,64] @ W2[64,16]) ----------------
__global__ __launch_bounds__(256) void k_gemm2(const float* __restrict__ h,
                                               const float* __restrict__ W,
                                               const float* __restrict__ dinv,
                                               float* __restrict__ h2) {
    __shared__ float Ws[64 * 16];
    __shared__ float xs[16][64];
    int t = threadIdx.x;
    for (int i = t; i < 64 * 16; i += 256) Ws[i] = W[i];
    long long row0 = (long long)blockIdx.x * 16;
    ((float4*)xs)[t] = ((const float4*)(h + row0 * 64))[t];
    __syncthreads();
    int r = t >> 4, c = t & 15;
    float acc = 0.f;
#pragma unroll
    for (int k = 0; k < 64; ++k) acc += xs[r][k] * Ws[k * 16 + c];
    h2[(row0 + r) * 16 + c] = dinv[row0 + r] * acc;
}

// ---------------- CSR aggregation, 64 feats: wave per node, lane = feature ----------------
// out1 = relu(dinv[d] * (self + sum_{s in N(d)} hs[s]) + b1)
__global__ __launch_bounds__(256) void k_agg64(const int* __restrict__ rowstart,
                                               const int* __restrict__ counts,
                                               const int* __restrict__ srcs,
                                               const float* __restrict__ hs,
                                               const float* __restrict__ dinv,
                                               const float* __restrict__ b,
                                               float* __restrict__ out, int n) {
    int d = (blockIdx.x * 256 + threadIdx.x) >> 6;  // node = global wave id
    if (d >= n) return;
    int f = threadIdx.x & 63;
    long long base = (long long)d * 64;
    float acc = hs[base + f];  // self-loop term
    int start = rowstart[d];
    int cnt = counts[d];
    if (cnt > 0) {
        int s0 = srcs[start];
        int k = 0;
        for (; k + 1 < cnt; ++k) {
            int s1 = srcs[start + k + 1];           // prefetch next src
            acc += hs[(long long)s0 * 64 + f];
            s0 = s1;
        }
        acc += hs[(long long)s0 * 64 + f];
    }
    float v = dinv[d] * acc + b[f];
    out[base + f] = fmaxf(v, 0.f);
}

// ---------------- CSR aggregation, 16 feats + fused log_softmax ----------------
__global__ __launch_bounds__(256) void k_agg16(const int* __restrict__ rowstart,
                                               const int* __restrict__ counts,
                                               const int* __restrict__ srcs,
                                               const float* __restrict__ hs,
                                               const float* __restrict__ dinv,
                                               const float* __restrict__ b,
                                               float* __restrict__ out, int n) {
    int g = (blockIdx.x * 256 + threadIdx.x) >> 4;  // node = 16-lane group
    if (g >= n) return;
    int f = threadIdx.x & 15;
    long long base = (long long)g * 16;
    float acc = hs[base + f];
    int start = rowstart[g];
    int cnt = counts[g];
    if (cnt > 0) {
        int s0 = srcs[start];
        int k = 0;
        for (; k + 1 < cnt; ++k) {
            int s1 = srcs[start + k + 1];
            acc += hs[(long long)s0 * 16 + f];
            s0 = s1;
        }
        acc += hs[(long long)s0 * 16 + f];
    }
    float v = dinv[g] * acc + b[f];
    float m = v;
#pragma unroll
    for (int o = 8; o >= 1; o >>= 1) m = fmaxf(m, __shfl_xor(m, o, 16));
    float ex = __expf(v - m);
#pragma unroll
    for (int o = 8; o >= 1; o >>= 1) ex += __shfl_xor(ex, o, 16);
    out[base + f] = (v - m) - __logf(ex);
}

extern "C" void kernel_launch(void* const* d_in, const int* in_sizes, int n_in,
                              void* d_out, int out_size, void* d_ws, size_t ws_size,
                              hipStream_t stream) {
    const float* x  = (const float*)d_in[0];
    const void*  ei = d_in[1];
    const float* W1 = (const float*)d_in[2];
    const float* b1 = (const float*)d_in[3];
    const float* W2 = (const float*)d_in[4];
    const float* b2 = (const float*)d_in[5];

    long long dh  = in_sizes[3];                 // 64
    long long din = in_sizes[2] / dh;            // 64
    long long n   = in_sizes[0] / din;           // 50000
    long long E   = (long long)in_sizes[1] / 2;  // 1.6M

    char* ws = (char*)d_ws;
    auto alloc = [&](size_t bytes) { void* p = ws; ws += (bytes + 255) & ~255ULL; return p; };
    int*   flag       = (int*)alloc(4);
    int*   counts     = (int*)alloc(n * 4);
    int*   rowstart   = (int*)alloc(n * 4);
    int*   cursor     = (int*)alloc(n * 4);
    int*   bsum       = (int*)alloc(THREADS * 4);
    int*   boff       = (int*)alloc(THREADS * 4);
    float* dinv       = (float*)alloc(n * 4);
    int*   sorted_src = (int*)alloc(E * 4);
    float* h1s        = (float*)alloc(n * 64 * 4);
    float* out1       = (float*)alloc(n * 64 * 4);
    float* h2s        = h1s;  // reuse: h1s dead after k_agg64, gemm2 runs after

    float* out = (float*)d_out;

    int nb = (int)((n + THREADS - 1) / THREADS);          // 196 (<=256 required)
    int eb = (int)((E + THREADS - 1) / THREADS);          // 6250

    hipMemsetAsync(counts, 0, (size_t)(n * 4), stream);

    k_detect<<<1, 1, 0, stream>>>(ei, n, flag);
    k_count<<<eb, THREADS, 0, stream>>>(ei, flag, E, counts);
    k_scanA<<<nb, THREADS, 0, stream>>>(counts, (int)n, rowstart, bsum, dinv);
    k_scanB<<<1, THREADS, 0, stream>>>(bsum, nb, boff);
    k_scanC<<<nb, THREADS, 0, stream>>>(rowstart, boff, cursor, (int)n);
    k_scatter<<<eb, THREADS, 0, stream>>>(ei, flag, E, cursor, sorted_src);

    // layer 1
    k_gemm1<<<(int)(n / 16), THREADS, 0, stream>>>(x, W1, dinv, h1s);
    k_agg64<<<(int)((n * 64 + 255) / 256), THREADS, 0, stream>>>(
        rowstart, counts, sorted_src, h1s, dinv, b1, out1, (int)n);

    // layer 2
    k_gemm2<<<(int)(n / 16), THREADS, 0, stream>>>(out1, W2, dinv, h2s);
    k_agg16<<<(int)((n * 16 + 255) / 256), THREADS, 0, stream>>>(
        rowstart, counts, sorted_src, h2s, dinv, b2, out, (int)n);
}